// Round 1
// baseline (127.359 us; speedup 1.0000x reference)
//
#include <hip/hip_runtime.h>

// Problem constants (from setup_inputs): N=8, C=256, H=W=64, A=9, bs=8, F=8, K=64, M=A*N*K=4608
constexpr int N_ = 8, C_ = 256, H_ = 64, W_ = 64, A_ = 9, F_ = 8, K_ = 64;
#define ALPHA_BS 0.8f   // ALPHA(0.1) * bs(8)

// ---------------------------------------------------------------------------
// Kernel 1: fused conv(reg) + tanh offset + bilinear sample -> rfb[M][C]
// One block per (n, gy, gx). Tile (256c x 8 x 8) staged in LDS as [e][c] with
// e = ly*8+lx, padded row (257) so both conv reads (lane=c) and sample reads
// (uniform e, lane=c) are bank-conflict-free.
// Offsets bounded by +-0.8 => all 4 bilinear corners are inside this block.
// ---------------------------------------------------------------------------
__global__ __launch_bounds__(256) void k_sample(const float* __restrict__ feat,
                                                const float* __restrict__ Wreg,
                                                const float* __restrict__ breg,
                                                float* __restrict__ rfb) {
    __shared__ float tile[64][257];   // [e][c]
    __shared__ float red[4][9];
    __shared__ float sW[9][4];
    __shared__ int   sI[9][4];

    const int b  = blockIdx.x;
    const int n  = b >> 6;
    const int gy = (b >> 3) & 7;
    const int gx = b & 7;
    const int t    = threadIdx.x;
    const int lane = t & 63;
    const int wid  = t >> 6;

    // ---- load 256c x 8x8 tile (4096 float4 total, 16 per thread) ----
    const float* fb = feat + ((size_t)n * C_ * H_ + gy * 8) * W_ + gx * 8;
#pragma unroll
    for (int it = 0; it < 16; ++it) {
        int q = t + 256 * it;
        int c = q >> 4, r = (q >> 1) & 7, h = q & 1;
        const float4 v = *(const float4*)(fb + ((size_t)c * H_ + r) * W_ + h * 4);
        int e = r * 8 + h * 4;
        tile[e + 0][c] = v.x;
        tile[e + 1][c] = v.y;
        tile[e + 2][c] = v.z;
        tile[e + 3][c] = v.w;
    }
    __syncthreads();

    // ---- conv: thread t owns channel c=t; 9 anchors ----
    float acc[9];
#pragma unroll
    for (int a = 0; a < 9; ++a) acc[a] = 0.f;
    const float* wbase = Wreg + (size_t)t * 64;
    for (int e4 = 0; e4 < 16; ++e4) {
        float t0 = tile[e4 * 4 + 0][t];
        float t1 = tile[e4 * 4 + 1][t];
        float t2 = tile[e4 * 4 + 2][t];
        float t3 = tile[e4 * 4 + 3][t];
#pragma unroll
        for (int a = 0; a < 9; ++a) {
            float4 w = *(const float4*)(wbase + (size_t)a * (C_ * 64) + e4 * 4);
            acc[a] = fmaf(t0, w.x, acc[a]);
            acc[a] = fmaf(t1, w.y, acc[a]);
            acc[a] = fmaf(t2, w.z, acc[a]);
            acc[a] = fmaf(t3, w.w, acc[a]);
        }
    }
    // wave reduce then cross-wave reduce
#pragma unroll
    for (int a = 0; a < 9; ++a) {
        float v = acc[a];
#pragma unroll
        for (int s = 32; s; s >>= 1) v += __shfl_xor(v, s, 64);
        if (lane == 0) red[wid][a] = v;
    }
    __syncthreads();
    if (t < 9) {
        float r   = red[0][t] + red[1][t] + red[2][t] + red[3][t] + breg[t];
        float off = ALPHA_BS * tanhf(r);
        float cx = 3.5f + 8.0f * gx + off;
        float cy = 3.5f + 8.0f * gy + off;
        float x0f = floorf(cx), y0f = floorf(cy);
        float wx = cx - x0f, wy = cy - y0f;
        int x0 = min(max((int)x0f, 0), W_ - 1);
        int x1 = min(x0 + 1, W_ - 1);
        int y0 = min(max((int)y0f, 0), H_ - 1);
        int y1 = min(y0 + 1, H_ - 1);
        int lx0 = x0 - gx * 8, lx1 = x1 - gx * 8;
        int ly0 = y0 - gy * 8, ly1 = y1 - gy * 8;
        sI[t][0] = ly0 * 8 + lx0;
        sI[t][1] = ly0 * 8 + lx1;
        sI[t][2] = ly1 * 8 + lx0;
        sI[t][3] = ly1 * 8 + lx1;
        sW[t][0] = (1.f - wx) * (1.f - wy);
        sW[t][1] = wx * (1.f - wy);
        sW[t][2] = (1.f - wx) * wy;
        sW[t][3] = wx * wy;
    }
    __syncthreads();

    // ---- sample: thread t = channel; write rfb[((a*N+n)*K + k)][c] ----
    const int kidx = gy * 8 + gx;
#pragma unroll
    for (int a = 0; a < 9; ++a) {
        float v = sW[a][0] * tile[sI[a][0]][t] + sW[a][1] * tile[sI[a][1]][t] +
                  sW[a][2] * tile[sI[a][2]][t] + sW[a][3] * tile[sI[a][3]][t];
        rfb[((size_t)(a * N_ + n) * K_ + kidx) * C_ + t] = v;
    }
}

// ---------------------------------------------------------------------------
// Kernel 2: rois_to_rois. One wave per (n,a,c) triple (18432 waves).
// lane = j over K=64. out[j] = b[j] + (sum_i e_i * a_i) / (sum_i e_i),
// e_i = exp(a_i*b_j - m_j), m_j = b_j>0 ? b_j*max(a) : b_j*min(a).
// NOTE: f1 and out may alias (stage 2 runs in place on d_out): each wave
// reads exactly the 64 values it later overwrites, ordered per-lane through
// the LDS round trip — safe. No __restrict__ on f1/out.
// ---------------------------------------------------------------------------
__global__ __launch_bounds__(256) void k_rois(const float* f1,
                                              const float* __restrict__ f2,
                                              float* out) {
    __shared__ float av[4][64];
    const int t    = threadIdx.x;
    const int lane = t & 63;
    const int wid  = t >> 6;
    const int w    = blockIdx.x * 4 + wid;   // [0, 18432)
    const int c    = w & 255;
    const int na   = w >> 8;                 // a*N + n
    const int base = na * K_;

    float a_ = f1[(size_t)(base + lane) * C_ + c];
    float b_ = f2[(size_t)(base + lane) * C_ + c];

    float mx = a_, mn = a_;
#pragma unroll
    for (int s = 32; s; s >>= 1) {
        mx = fmaxf(mx, __shfl_xor(mx, s, 64));
        mn = fminf(mn, __shfl_xor(mn, s, 64));
    }
    av[wid][lane] = a_;
    __syncthreads();

    const float m = b_ > 0.f ? b_ * mx : b_ * mn;
    float den = 0.f, num = 0.f;
#pragma unroll
    for (int i = 0; i < 64; ++i) {
        float ai = av[wid][i];
        float e  = __expf(fmaf(ai, b_, -m));
        den += e;
        num = fmaf(e, ai, num);
    }
    out[(size_t)(base + lane) * C_ + c] = b_ + num / den;
}

// ---------------------------------------------------------------------------
extern "C" void kernel_launch(void* const* d_in, const int* in_sizes, int n_in,
                              void* d_out, int out_size, void* d_ws, size_t ws_size,
                              hipStream_t stream) {
    // input order: ori_feature_shape, rois_feature_a, feature_b, rois_feature_c, W_reg, b_reg
    const float* rois_a = (const float*)d_in[1];
    const float* feat   = (const float*)d_in[2];
    const float* rois_c = (const float*)d_in[3];
    const float* Wreg   = (const float*)d_in[4];
    const float* breg   = (const float*)d_in[5];
    float* out = (float*)d_out;
    float* rfb = (float*)d_ws;   // M*C floats = 4.72 MB scratch

    k_sample<<<dim3(N_ * F_ * F_), dim3(256), 0, stream>>>(feat, Wreg, breg, rfb);
    // stage 1: out1 -> d_out
    k_rois<<<dim3((A_ * N_ * C_ * 64) / 256), dim3(256), 0, stream>>>(rois_a, rfb, out);
    // stage 2: in place on d_out
    k_rois<<<dim3((A_ * N_ * C_ * 64) / 256), dim3(256), 0, stream>>>(out, rois_c, out);
}

// Round 2
// 91.338 us; speedup vs baseline: 1.3944x; 1.3944x over previous
//
#include <hip/hip_runtime.h>

// N=8, C=256, H=W=64, A=9, bs=8, F=8, K=64, M=A*N*K=4608
constexpr int N_ = 8, C_ = 256, H_ = 64, W_ = 64, A_ = 9, F_ = 8, K_ = 64;
#define ALPHA_BS 0.8f   // ALPHA(0.1) * bs(8)
#define L2E 1.442695040888963f

// ---------------------------------------------------------------------------
// Kernel 1: fused conv(reg) + tanh offset + bilinear sample -> rfb[M][C]
// One block per (n,gy,gx), XCD-swizzled so XCD x owns image n=x (L2 locality,
// kills the 2x line-split over-fetch). Tile staged [c][e] (row stride 68) so
// conv does ds_read_b128 at the bank floor and W loads are lane-coalesced:
// per anchor, thread t owns flat W elements j*1024 + 4t .. +3 (j=0..15) ->
// global_load_dwordx4 with consecutive lanes = 1KB coalesced per instruction.
// Offsets bounded by +-0.8 => all 4 bilinear corners inside this 8x8 block.
// ---------------------------------------------------------------------------
__global__ __launch_bounds__(256) void k_sample(const float* __restrict__ feat,
                                                const float* __restrict__ Wreg,
                                                const float* __restrict__ breg,
                                                float* __restrict__ rfb) {
    __shared__ float tile[256][68];   // [c][e], 69.6 KB
    __shared__ float red[4][9];
    __shared__ float sW[9][4];
    __shared__ int   sI[9][4];

    const int bi = blockIdx.x;
    const int b  = (bi & 7) * 64 + (bi >> 3);   // XCD x -> n = x
    const int n  = b >> 6;
    const int gy = (b >> 3) & 7;
    const int gx = b & 7;
    const int t    = threadIdx.x;
    const int lane = t & 63;
    const int wid  = t >> 6;

    // ---- stage 256c x 8x8 tile ----
    const float* fb = feat + ((size_t)n * C_ * H_ + gy * 8) * W_ + gx * 8;
#pragma unroll
    for (int it = 0; it < 16; ++it) {
        int q = t + 256 * it;
        int c = q >> 4, r = (q >> 1) & 7, h = q & 1;
        float4 v = *(const float4*)(fb + ((size_t)c * H_ + r) * W_ + h * 4);
        *(float4*)&tile[c][r * 8 + h * 4] = v;
    }
    __syncthreads();

    // ---- conv: thread t owns flat elements 4t + 1024j; W loads coalesced ----
    float acc[9];
#pragma unroll
    for (int a = 0; a < 9; ++a) acc[a] = 0.f;
    const float* wt = Wreg + 4 * t;
#pragma unroll
    for (int j = 0; j < 16; ++j) {
        const int c = j * 16 + (t >> 4);
        const float4 t4 = *(const float4*)&tile[c][4 * (t & 15)];
#pragma unroll
        for (int a = 0; a < 9; ++a) {
            const float4 w4 = *(const float4*)(wt + (size_t)a * 16384 + j * 1024);
            acc[a] = fmaf(t4.x, w4.x, acc[a]);
            acc[a] = fmaf(t4.y, w4.y, acc[a]);
            acc[a] = fmaf(t4.z, w4.z, acc[a]);
            acc[a] = fmaf(t4.w, w4.w, acc[a]);
        }
    }
#pragma unroll
    for (int a = 0; a < 9; ++a) {
        float v = acc[a];
#pragma unroll
        for (int s = 32; s; s >>= 1) v += __shfl_xor(v, s, 64);
        if (lane == 0) red[wid][a] = v;
    }
    __syncthreads();
    if (t < 9) {
        float r   = red[0][t] + red[1][t] + red[2][t] + red[3][t] + breg[t];
        float off = ALPHA_BS * tanhf(r);
        float cx = 3.5f + 8.0f * gx + off;
        float cy = 3.5f + 8.0f * gy + off;
        float x0f = floorf(cx), y0f = floorf(cy);
        float wx = cx - x0f, wy = cy - y0f;
        int x0 = min(max((int)x0f, 0), W_ - 1);
        int x1 = min(x0 + 1, W_ - 1);
        int y0 = min(max((int)y0f, 0), H_ - 1);
        int y1 = min(y0 + 1, H_ - 1);
        int lx0 = x0 - gx * 8, lx1 = x1 - gx * 8;
        int ly0 = y0 - gy * 8, ly1 = y1 - gy * 8;
        sI[t][0] = ly0 * 8 + lx0;
        sI[t][1] = ly0 * 8 + lx1;
        sI[t][2] = ly1 * 8 + lx0;
        sI[t][3] = ly1 * 8 + lx1;
        sW[t][0] = (1.f - wx) * (1.f - wy);
        sW[t][1] = wx * (1.f - wy);
        sW[t][2] = (1.f - wx) * wy;
        sW[t][3] = wx * wy;
    }
    __syncthreads();

    // ---- sample: thread t = channel c; coalesced store ----
    const int kidx = gy * 8 + gx;
#pragma unroll
    for (int a = 0; a < 9; ++a) {
        float v = sW[a][0] * tile[t][sI[a][0]] + sW[a][1] * tile[t][sI[a][1]] +
                  sW[a][2] * tile[t][sI[a][2]] + sW[a][3] * tile[t][sI[a][3]];
        rfb[((size_t)(a * N_ + n) * K_ + kidx) * C_ + t] = v;
    }
}

// ---------------------------------------------------------------------------
// Kernel 2: rois_to_rois. Block = (na, 16-channel chunk): 72*16 = 1152 blocks.
// Stage a,b chunks [64][16] in LDS (coalesced 64B-segment loads). Compute:
// wave w handles 4 channels; lane = j. Inner K-loop: a_i broadcast to SGPR via
// v_readlane (no LDS in loop), e = exp2(fma(a_i, b*log2e, -m*log2e)).
// Results staged in LDS, written back coalesced. Stage 2 runs in place on
// d_out: each block reads exactly the region it overwrites (barrier-ordered).
// ---------------------------------------------------------------------------
__global__ __launch_bounds__(256) void k_rois(const float* f1,
                                              const float* __restrict__ f2,
                                              float* out) {
    __shared__ float sa[64][17];
    __shared__ float sb[64][17];
    __shared__ float so[64][17];

    const int bi = blockIdx.x;
    const int b  = (bi & 7) * 144 + (bi >> 3);  // XCD-chunked
    const int na = b >> 4;
    const int cb = (b & 15) * 16;
    const int t = threadIdx.x, lane = t & 63, w = t >> 6;
    const size_t base = (size_t)na * 64;

#pragma unroll
    for (int k = 0; k < 4; ++k) {
        int idx = t + 256 * k;
        int i = idx >> 4, cc = idx & 15;
        sa[i][cc] = f1[(base + i) * 256 + cb + cc];
        sb[i][cc] = f2[(base + i) * 256 + cb + cc];
    }
    __syncthreads();

#pragma unroll
    for (int ci = 0; ci < 4; ++ci) {
        const int cc = w * 4 + ci;
        const float a_ = sa[lane][cc];
        const float b_ = sb[lane][cc];
        float mx = a_, mn = a_;
#pragma unroll
        for (int s = 32; s; s >>= 1) {
            mx = fmaxf(mx, __shfl_xor(mx, s, 64));
            mn = fminf(mn, __shfl_xor(mn, s, 64));
        }
        const float m   = b_ > 0.f ? b_ * mx : b_ * mn;
        const float bl2 = b_ * L2E;
        const float ml2 = -m * L2E;
        float den = 0.f, num = 0.f;
#pragma unroll
        for (int i = 0; i < 64; ++i) {
            const float ai = __int_as_float(__builtin_amdgcn_readlane(__float_as_int(a_), i));
            const float e  = __builtin_amdgcn_exp2f(fmaf(ai, bl2, ml2));
            den += e;
            num = fmaf(e, ai, num);
        }
        so[lane][cc] = b_ + num / den;
    }
    __syncthreads();

#pragma unroll
    for (int k = 0; k < 4; ++k) {
        int idx = t + 256 * k;
        int i = idx >> 4, cc = idx & 15;
        out[(base + i) * 256 + cb + cc] = so[i][cc];
    }
}

// ---------------------------------------------------------------------------
extern "C" void kernel_launch(void* const* d_in, const int* in_sizes, int n_in,
                              void* d_out, int out_size, void* d_ws, size_t ws_size,
                              hipStream_t stream) {
    // inputs: ori_feature_shape, rois_feature_a, feature_b, rois_feature_c, W_reg, b_reg
    const float* rois_a = (const float*)d_in[1];
    const float* feat   = (const float*)d_in[2];
    const float* rois_c = (const float*)d_in[3];
    const float* Wreg   = (const float*)d_in[4];
    const float* breg   = (const float*)d_in[5];
    float* out = (float*)d_out;
    float* rfb = (float*)d_ws;   // M*C floats = 4.72 MB scratch

    k_sample<<<dim3(N_ * F_ * F_), dim3(256), 0, stream>>>(feat, Wreg, breg, rfb);
    k_rois<<<dim3(A_ * N_ * (C_ / 16)), dim3(256), 0, stream>>>(rois_a, rfb, out);
    k_rois<<<dim3(A_ * N_ * (C_ / 16)), dim3(256), 0, stream>>>(out, rois_c, out);
}

// Round 3
// 67.335 us; speedup vs baseline: 1.8914x; 1.3565x over previous
//
#include <hip/hip_runtime.h>

// N=8, C=256, H=W=64, A=9, bs=8, F=8, K=64, M=A*N*K=4608
constexpr int N_ = 8, C_ = 256, H_ = 64, W_ = 64, A_ = 9, F_ = 8, K_ = 64;
constexpr int M_ = A_ * N_ * K_;
#define ALPHA_BS 0.8f   // ALPHA(0.1) * bs(8)
#define L2E 1.442695040888963f

// ---------------------------------------------------------------------------
// Kernel 1a: conv partials. Grid 4096 = 512 positions x 8 channel-chunks.
// chunk = blockIdx%8 == XCD id -> each XCD L2 holds one 73.7KB W slice and
// one 4.2MB feat channel slice. Thread t owns flat q = chunk*2048 + t*8..+7
// (channel cl=t>>3, row r=t&7, 8 contiguous cols): feat = 2 float4 loads,
// W = 18 float4 loads, consecutive lanes contiguous (1KB/instruction).
// 72 FMAs -> 9 accs -> wave reduce -> partials[p][a][chunk].
// ---------------------------------------------------------------------------
__global__ __launch_bounds__(256) void k_conv(const float* __restrict__ feat,
                                              const float* __restrict__ Wreg,
                                              float* __restrict__ partials) {
    __shared__ float red[4][9];
    const int bi = blockIdx.x;
    const int p = bi >> 3, chunk = bi & 7;
    const int n = p >> 6, gy = (p >> 3) & 7, gx = p & 7;
    const int t = threadIdx.x, lane = t & 63, wid = t >> 6;
    const int cl = t >> 3;          // local channel 0..31
    const int r  = t & 7;           // patch row 0..7
    const int c  = chunk * 32 + cl;

    const float* fp = feat + (((size_t)n * C_ + c) * H_ + gy * 8 + r) * W_ + gx * 8;
    const float4 f0 = *(const float4*)fp;
    const float4 f1 = *(const float4*)(fp + 4);

    const float* wp = Wreg + chunk * 2048 + t * 8;
    float acc[9];
#pragma unroll
    for (int a = 0; a < 9; ++a) {
        const float4 w0 = *(const float4*)(wp + (size_t)a * 16384);
        const float4 w1 = *(const float4*)(wp + (size_t)a * 16384 + 4);
        float s = f0.x * w0.x + f0.y * w0.y + f0.z * w0.z + f0.w * w0.w;
        s = fmaf(f1.x, w1.x, s);
        s = fmaf(f1.y, w1.y, s);
        s = fmaf(f1.z, w1.z, s);
        s = fmaf(f1.w, w1.w, s);
        acc[a] = s;
    }
#pragma unroll
    for (int a = 0; a < 9; ++a) {
        float v = acc[a];
#pragma unroll
        for (int s = 32; s; s >>= 1) v += __shfl_xor(v, s, 64);
        if (lane == 0) red[wid][a] = v;
    }
    __syncthreads();
    if (t < 9) {
        partials[(size_t)p * 72 + t * 8 + chunk] =
            red[0][t] + red[1][t] + red[2][t] + red[3][t];
    }
}

// ---------------------------------------------------------------------------
// Kernel 1b: offsets + bilinear sample -> rfb[M][C].
// One block per position (XCD-swizzled: XCD x -> image n=x). Threads 0..8
// finish the conv (8 contiguous partials each + bias -> tanh -> weights +
// corner indices); all threads stage the 256c x 8x8 tile [c][e] (float4 LDS,
// stride 68 keeps it conflict-light); sample 9 anchors from LDS, coalesced
// stores. Offsets bounded by +-0.8 => corners stay inside this 8x8 block.
// ---------------------------------------------------------------------------
__global__ __launch_bounds__(256) void k_samp(const float* __restrict__ feat,
                                              const float* __restrict__ partials,
                                              const float* __restrict__ breg,
                                              float* __restrict__ rfb) {
    __shared__ float tile[256][68];   // [c][e]
    __shared__ float sW[9][4];
    __shared__ int   sI[9][4];

    const int bi = blockIdx.x;
    const int b  = (bi & 7) * 64 + (bi >> 3);
    const int n  = b >> 6, gy = (b >> 3) & 7, gx = b & 7;
    const int p  = b;                  // same ordering as k_conv
    const int t  = threadIdx.x;

    if (t < 9) {
        const float* pp = partials + (size_t)p * 72 + t * 8;
        float r = breg[t];
#pragma unroll
        for (int c = 0; c < 8; ++c) r += pp[c];
        float off = ALPHA_BS * tanhf(r);
        float cx = 3.5f + 8.0f * gx + off;
        float cy = 3.5f + 8.0f * gy + off;
        float x0f = floorf(cx), y0f = floorf(cy);
        float wx = cx - x0f, wy = cy - y0f;
        int x0 = min(max((int)x0f, 0), W_ - 1);
        int x1 = min(x0 + 1, W_ - 1);
        int y0 = min(max((int)y0f, 0), H_ - 1);
        int y1 = min(y0 + 1, H_ - 1);
        int lx0 = x0 - gx * 8, lx1 = x1 - gx * 8;
        int ly0 = y0 - gy * 8, ly1 = y1 - gy * 8;
        sI[t][0] = ly0 * 8 + lx0;
        sI[t][1] = ly0 * 8 + lx1;
        sI[t][2] = ly1 * 8 + lx0;
        sI[t][3] = ly1 * 8 + lx1;
        sW[t][0] = (1.f - wx) * (1.f - wy);
        sW[t][1] = wx * (1.f - wy);
        sW[t][2] = (1.f - wx) * wy;
        sW[t][3] = wx * wy;
    }

    const float* fb = feat + ((size_t)n * C_ * H_ + gy * 8) * W_ + gx * 8;
#pragma unroll
    for (int it = 0; it < 16; ++it) {
        int q = t + 256 * it;
        int c = q >> 4, r = (q >> 1) & 7, h = q & 1;
        float4 v = *(const float4*)(fb + ((size_t)c * H_ + r) * W_ + h * 4);
        *(float4*)&tile[c][r * 8 + h * 4] = v;
    }
    __syncthreads();

    const int kidx = gy * 8 + gx;
#pragma unroll
    for (int a = 0; a < 9; ++a) {
        float v = sW[a][0] * tile[t][sI[a][0]] + sW[a][1] * tile[t][sI[a][1]] +
                  sW[a][2] * tile[t][sI[a][2]] + sW[a][3] * tile[t][sI[a][3]];
        rfb[((size_t)(a * N_ + n) * K_ + kidx) * C_ + t] = v;
    }
}

// ---------------------------------------------------------------------------
// Kernel 2: rois_to_rois. Block = (na, 16-channel chunk): 72*16 = 1152 blocks.
// Stage a,b chunks [64][16] in LDS (coalesced). Wave w handles 4 channels;
// lane = j. Inner K-loop: a_i broadcast via readlane, e = exp2(fma). Results
// staged in LDS, written back coalesced. Stage 2 runs in place on d_out: each
// block reads exactly the region it overwrites (barrier-ordered).
// ---------------------------------------------------------------------------
__global__ __launch_bounds__(256) void k_rois(const float* f1,
                                              const float* __restrict__ f2,
                                              float* out) {
    __shared__ float sa[64][17];
    __shared__ float sb[64][17];
    __shared__ float so[64][17];

    const int bi = blockIdx.x;
    const int b  = (bi & 7) * 144 + (bi >> 3);  // XCD-chunked
    const int na = b >> 4;
    const int cb = (b & 15) * 16;
    const int t = threadIdx.x, lane = t & 63, w = t >> 6;
    const size_t base = (size_t)na * 64;

#pragma unroll
    for (int k = 0; k < 4; ++k) {
        int idx = t + 256 * k;
        int i = idx >> 4, cc = idx & 15;
        sa[i][cc] = f1[(base + i) * 256 + cb + cc];
        sb[i][cc] = f2[(base + i) * 256 + cb + cc];
    }
    __syncthreads();

#pragma unroll
    for (int ci = 0; ci < 4; ++ci) {
        const int cc = w * 4 + ci;
        const float a_ = sa[lane][cc];
        const float b_ = sb[lane][cc];
        float mx = a_, mn = a_;
#pragma unroll
        for (int s = 32; s; s >>= 1) {
            mx = fmaxf(mx, __shfl_xor(mx, s, 64));
            mn = fminf(mn, __shfl_xor(mn, s, 64));
        }
        const float m   = b_ > 0.f ? b_ * mx : b_ * mn;
        const float bl2 = b_ * L2E;
        const float ml2 = -m * L2E;
        float den = 0.f, num = 0.f;
#pragma unroll
        for (int i = 0; i < 64; ++i) {
            const float ai = __int_as_float(__builtin_amdgcn_readlane(__float_as_int(a_), i));
            const float e  = __builtin_amdgcn_exp2f(fmaf(ai, bl2, ml2));
            den += e;
            num = fmaf(e, ai, num);
        }
        so[lane][cc] = b_ + num / den;
    }
    __syncthreads();

#pragma unroll
    for (int k = 0; k < 4; ++k) {
        int idx = t + 256 * k;
        int i = idx >> 4, cc = idx & 15;
        out[(base + i) * 256 + cb + cc] = so[i][cc];
    }
}

// ---------------------------------------------------------------------------
extern "C" void kernel_launch(void* const* d_in, const int* in_sizes, int n_in,
                              void* d_out, int out_size, void* d_ws, size_t ws_size,
                              hipStream_t stream) {
    // inputs: ori_feature_shape, rois_feature_a, feature_b, rois_feature_c, W_reg, b_reg
    const float* rois_a = (const float*)d_in[1];
    const float* feat   = (const float*)d_in[2];
    const float* rois_c = (const float*)d_in[3];
    const float* Wreg   = (const float*)d_in[4];
    const float* breg   = (const float*)d_in[5];
    float* out = (float*)d_out;
    float* partials = (float*)d_ws;                 // 512*72 floats = 147 KB
    float* rfb = (float*)d_ws + 512 * 72;           // M*C floats = 4.72 MB

    k_conv<<<dim3(512 * 8), dim3(256), 0, stream>>>(feat, Wreg, partials);
    k_samp<<<dim3(N_ * F_ * F_), dim3(256), 0, stream>>>(feat, partials, breg, rfb);
    k_rois<<<dim3(A_ * N_ * (C_ / 16)), dim3(256), 0, stream>>>(rois_a, rfb, out);
    k_rois<<<dim3(A_ * N_ * (C_ / 16)), dim3(256), 0, stream>>>(out, rois_c, out);
}